// Round 16
// baseline (342.214 us; speedup 1.0000x reference)
//
#include <hip/hip_runtime.h>
#include <hip/hip_fp16.h>
#include <math.h>

#define DEPTH 6
#define HEADS 8
#define BB    2
#define NN    128
#define EE    160
#define NF    127
#define DIMM  128
#define INNER 512
#define NNODE 256

__device__ __forceinline__ void gload16(const void* g, void* l) {
    __builtin_amdgcn_global_load_lds((const __attribute__((address_space(1))) void*)g,
                                     (__attribute__((address_space(3))) void*)l,
                                     16, 0, 0);
}

// wait this wave's outstanding vmem (vmcnt(0); lgkm/exp unconstrained)
__device__ __forceinline__ void wait_vm0() { __builtin_amdgcn_s_waitcnt(0x0f70); }
// drain this wave's LDS ops before slice overwrite
__device__ __forceinline__ void wait_lgkm0() { __builtin_amdgcn_s_waitcnt(0xC07F); }

// Per-wave 16 KB contiguous stage: 16 x (1 KB gload16). ldsslice wave-uniform.
__device__ __forceinline__ void wstage16(const char* gslice, char* ldsslice, int ln) {
#pragma unroll
    for (int i = 0; i < 16; i++)
        gload16(gslice + i * 1024 + ln * 16, ldsslice + i * 1024);
}

// Stage a 128-byte-wide column stripe over 128 rows (16 KB) into the wave slice.
// gcolbase already includes the stripe's column byte offset. LDS ends up
// row-major with 128 B rows: row r at ldsslice + r*128.
__device__ __forceinline__ void wstage_stripe(const char* gcolbase, int rowstride,
                                              char* ldsslice, int ln) {
#pragma unroll
    for (int i = 0; i < 16; i++)
        gload16(gcolbase + (size_t)(i * 8 + (ln >> 3)) * rowstride + (ln & 7) * 16,
                ldsslice + i * 1024);
}

// Col-split GEMV, C=512 K=128: wave owns cols [w*64, w*64+64) (staged stripe,
// row-major 128 B rows). lane: p = ln&31 (col pair), rh = ln>>5 (row half).
// Returns sums for cols (w*64+2p, +1) on ALL lanes (xor-merge symmetric).
__device__ __forceinline__ float2 gemv512cs(const float* act, const float* wbuf, int ln) {
    int p = ln & 31, rh = ln >> 5;
    const float* base = wbuf + rh * 64 * 32;
    const float* a    = act + rh * 64;
    float2 acc = {0.0f, 0.0f};
#pragma unroll 8
    for (int k = 0; k < 64; k++) {
        float raw = base[k * 32 + p];
        float2 pr = __half22float2(*(const __half2*)&raw);
        acc.x += a[k] * pr.x;
        acc.y += a[k] * pr.y;
    }
    acc.x += __shfl_xor(acc.x, 32, 64);
    acc.y += __shfl_xor(acc.y, 32, 64);
    return acc;
}

// K-split GEMV, C=128 K=512: wave owns rows [w*64, w*64+64) (contig slice).
// lane ln accumulates col pair (2ln, 2ln+1); partials to s_part.
__device__ __forceinline__ void gemv128(const float* act, const float* wbuf,
                                        float* s_part, int w, int ln) {
    float2 acc = {0.0f, 0.0f};
#pragma unroll 8
    for (int r = 0; r < 64; r++) {
        float raw = wbuf[r * 64 + ln];
        float2 p = __half22float2(*(const __half2*)&raw);
        float a = act[w * 64 + r];
        acc.x += a * p.x; acc.y += a * p.y;
    }
    s_part[w * 128 + ln * 2]     = acc.x;
    s_part[w * 128 + ln * 2 + 1] = acc.y;
}

// N-value block reduce (8 waves); results broadcast into vals[].
template <int N>
__device__ __forceinline__ void block_reduce_n(float* vals, float* sbuf) {
#pragma unroll
    for (int off = 32; off > 0; off >>= 1)
#pragma unroll
        for (int q = 0; q < N; q++) vals[q] += __shfl_xor(vals[q], off, 64);
    int wave = threadIdx.x >> 6;
    if ((threadIdx.x & 63) == 0)
#pragma unroll
        for (int q = 0; q < N; q++) sbuf[wave * N + q] = vals[q];
    __syncthreads();
#pragma unroll
    for (int q = 0; q < N; q++) {
        float r = 0.0f;
#pragma unroll
        for (int g = 0; g < 8; g++) r += sbuf[g * N + q];
        vals[q] = r;
    }
    __syncthreads();
}

__device__ __forceinline__ float gelu_exact(float a) {
    return 0.5f * a * (1.0f + erff(a * 0.70710678f));
}

// ---------- kernels ----------

__global__ __launch_bounds__(512) void k_cvt(const float* Wq, const float* Wkv,
                                             const float* Wo, const float* W1,
                                             const float* W2,
                                             __half* hWq, __half* hWkv, __half* hWo,
                                             __half* hW1, __half* hW2,
                                             const float* blin, float* out) {
    if (blockIdx.x == 0 && threadIdx.x == 0) out[0] = 256.0f * blin[0];
    int g = blockIdx.x * 512 + threadIdx.x;
    const float4* src; __half* dst; int off;
    if (g < 98304)       { src = (const float4*)Wq;  dst = hWq;  off = g; }
    else if (g < 294912) { src = (const float4*)Wkv; dst = hWkv; off = g - 98304; }
    else if (g < 393216) { src = (const float4*)Wo;  dst = hWo;  off = g - 294912; }
    else if (g < 491520) { src = (const float4*)W1;  dst = hW1;  off = g - 393216; }
    else                 { src = (const float4*)W2;  dst = hW2;  off = g - 491520; }
    float4 v = src[off];
    __half2* d2 = (__half2*)(dst + (size_t)off * 4);
    d2[0] = __floats2half2_rn(v.x, v.y);
    d2[1] = __floats2half2_rn(v.z, v.w);
}

__global__ __launch_bounds__(512, 1) void k_pre(const int* indices, const float* noise,
                                                const float* atom_emb,
                                                const float* ln1_g, const float* ln1_b,
                                                const __half* hWq, const float* bq,
                                                const __half* hWkv, const float* bkv,
                                                float* nodes, float* qb,
                                                __half* hk, __half* hv) {
    int bn = blockIdx.x;
    int t  = threadIdx.x;
    int d  = t & 127;
    bool own = (t < 128);
    int w = t >> 6, ln = t & 63;
    __shared__ float arena[32768];
    __shared__ float s_xn[128];
    __shared__ float s_red[48];
    char*  lslice = (char*)arena + w * 16384;
    float* wbuf   = arena + w * 4096;

    const char* WqL  = (const char*)hWq;
    const char* WkvL = (const char*)hWkv;
    // stage Wq col-stripe; DMA overlaps gather + LN
    wstage_stripe(WqL + w * 128, 1024, lslice, ln);

    float nd = 0.0f;
    if (own) {
        int idx = indices[bn];
        nd = (d < NF) ? atom_emb[idx * NF + d] : noise[0];
        nodes[bn * DIMM + d] = nd;
    }
    float vals[2] = {own ? nd : 0.0f, own ? nd * nd : 0.0f};
    block_reduce_n<2>(vals, s_red);
    float m   = vals[0] * (1.0f / 128.0f);
    float var = vals[1] * (1.0f / 128.0f) - m * m;
    if (own) s_xn[d] = (nd - m) * rsqrtf(var + 1e-5f) * ln1_g[d] + ln1_b[d];
    __syncthreads();

    int p = ln & 31;
    int cg = w * 64 + 2 * p;   // global col of .x

    // Wq
    wait_vm0();
    float2 q2 = gemv512cs(s_xn, wbuf, ln);
    wait_lgkm0();
    wstage_stripe(WkvL + w * 128, 2048, lslice, ln);   // Wk stripe
    if (ln < 32) {
        float2 o; o.x = q2.x + bq[cg]; o.y = q2.y + bq[cg + 1];
        ((float2*)(qb + (size_t)bn * INNER))[w * 32 + p] = o;
    }

    // Wk
    wait_vm0();
    float2 k2 = gemv512cs(s_xn, wbuf, ln);
    wait_lgkm0();
    wstage_stripe(WkvL + 1024 + w * 128, 2048, lslice, ln);   // Wv stripe
    if (ln < 32)
        ((__half2*)(hk + (size_t)bn * INNER))[w * 32 + p] =
            __floats2half2_rn(k2.x + bkv[cg], k2.y + bkv[cg + 1]);

    // Wv
    wait_vm0();
    float2 v2 = gemv512cs(s_xn, wbuf, ln);
    if (ln < 32)
        ((__half2*)(hv + (size_t)bn * INNER))[w * 32 + p] =
            __floats2half2_rn(v2.x + bkv[INNER + cg], v2.y + bkv[INNER + cg + 1]);
}

__global__ __launch_bounds__(512, 1) void k_layer(int l,
        const float* coords, const int* bonds,
        const float* We, const float* be,
        float* qb, const __half* hkin, const __half* hvin,
        __half* hkout, __half* hvout,
        const __half* hWo, const float* bo, const float* Wg1,
        const float* ln2_g, const float* ln2_b,
        const __half* hW1, const float* b1,
        const __half* hW2, const float* b2,
        const float* Wg2,
        const float* ln1_g, const float* ln1_b,
        const __half* hWq, const float* bq,
        const __half* hWkv, const float* bkv,
        float* nodes, const float* Wlin, float* out) {
    int bn = blockIdx.x;
    int b = bn >> 7, i = bn & 127;
    int t = threadIdx.x;
    int d = t & 127;
    bool own = (t < 128);
    int w = t >> 6, ln = t & 63;

    __shared__ float arena[32768];     // per-wave weight slices (16 KB each)
    __shared__ float scoord[384];
    __shared__ float sedge[384];
    __shared__ int   sbonds[2 * EE];
    __shared__ float s_l[64];
    __shared__ float s_ao[512];
    __shared__ float s_h[512];
    __shared__ float s_xn[128];
    __shared__ float s_red[48];
    __shared__ float s_part[4096];     // aliased as s_o (8 waves x 512) in attention
    float* s_o = s_part;
    char*  lslice = (char*)arena + w * 16384;
    float* wbuf   = arena + w * 4096;

    const char* WoL  = (const char*)(hWo + (size_t)l * INNER * DIMM);
    const char* W1L  = (const char*)(hW1 + (size_t)l * DIMM * 4 * DIMM);
    const char* W2L  = (const char*)(hW2 + (size_t)l * 4 * DIMM * DIMM);
    const char* WqL  = (const char*)(hWq + (size_t)(l + 1) * DIMM * INNER);
    const char* WkvL = (const char*)(hWkv + (size_t)(l + 1) * DIMM * 2 * INNER);

    // stage Wo (contiguous K-slice); DMA overlaps the whole attention phase
    wstage16(WoL + w * 16384, lslice, ln);

    // ---------- attention: wave w owns j in [w*16, w*16+16); 64 lanes = 512 dims ----------
    const float4* qR4 = (const float4*)(qb + (size_t)bn * INNER);
    const float4* WeR = (const float4*)(We + (size_t)l * 3 * INNER);
    float4 qa  = qR4[ln * 2],        qz  = qR4[ln * 2 + 1];
    float4 w0a = WeR[ln * 2],        w0z = WeR[ln * 2 + 1];
    float4 w1a = WeR[128 + ln * 2],  w1z = WeR[129 + ln * 2];
    float4 w2a = WeR[256 + ln * 2],  w2z = WeR[257 + ln * 2];
    float4 bea = ((const float4*)(be + (size_t)l * INNER))[ln * 2];
    float4 bez = ((const float4*)(be + (size_t)l * INNER))[ln * 2 + 1];
    float res = own ? nodes[bn * DIMM + d] : 0.0f;

    if (t < 2 * EE) sbonds[t] = bonds[t];
    if (t < 3 * NN) scoord[t] = coords[b * 3 * NN + t];
    __syncthreads();
    if (t < NN) {
        int j = t;
        float msk = 0.0f;
        for (int e = 0; e < EE; e++) {
            int e0 = sbonds[2 * e], e1 = sbonds[2 * e + 1];
            if ((e0 == i && e1 == j) || (e1 == i && e0 == j)) msk = 1.0f;
        }
        sedge[3 * j + 0] = msk * (scoord[3 * i + 0] - scoord[3 * j + 0]);
        sedge[3 * j + 1] = msk * (scoord[3 * i + 1] - scoord[3 * j + 1]);
        sedge[3 * j + 2] = msk * (scoord[3 * i + 2] - scoord[3 * j + 2]);
    }
    __syncthreads();

    const float4* kR = (const float4*)(hkin + (size_t)b * NN * INNER);   // 8 halves/elt
    const float4* vR = (const float4*)(hvin + (size_t)b * NN * INNER);
    float l_run = 0.0f;
    float4 o0 = {0, 0, 0, 0}, o1 = {0, 0, 0, 0};
    int j0 = w * 16;
#pragma unroll
    for (int base = 0; base < 16; base += 4) {
        float4 kraw[4], vraw[4];
#pragma unroll
        for (int p = 0; p < 4; p++) {
            int j = j0 + base + p;
            kraw[p] = kR[j * 64 + ln];
            vraw[p] = vR[j * 64 + ln];
        }
#pragma unroll
        for (int p = 0; p < 4; p++) {
            int j = j0 + base + p;
            float ex = sedge[3 * j], ey = sedge[3 * j + 1], ez = sedge[3 * j + 2];
            float4 e0, e1;
            e0.x = bea.x + ex * w0a.x + ey * w1a.x + ez * w2a.x;
            e0.y = bea.y + ex * w0a.y + ey * w1a.y + ez * w2a.y;
            e0.z = bea.z + ex * w0a.z + ey * w1a.z + ez * w2a.z;
            e0.w = bea.w + ex * w0a.w + ey * w1a.w + ez * w2a.w;
            e1.x = bez.x + ex * w0z.x + ey * w1z.x + ez * w2z.x;
            e1.y = bez.y + ex * w0z.y + ey * w1z.y + ez * w2z.y;
            e1.z = bez.z + ex * w0z.z + ey * w1z.z + ez * w2z.z;
            e1.w = bez.w + ex * w0z.w + ey * w1z.w + ez * w2z.w;
            const __half2* kh = (const __half2*)&kraw[p];
            float2 k0 = __half22float2(kh[0]), k1 = __half22float2(kh[1]);
            float2 k2 = __half22float2(kh[2]), k3 = __half22float2(kh[3]);
            float s = qa.x * (k0.x + e0.x) + qa.y * (k0.y + e0.y)
                    + qa.z * (k1.x + e0.z) + qa.w * (k1.y + e0.w)
                    + qz.x * (k2.x + e1.x) + qz.y * (k2.y + e1.y)
                    + qz.z * (k3.x + e1.z) + qz.w * (k3.y + e1.w);
            s += __shfl_xor(s, 1, 64);
            s += __shfl_xor(s, 2, 64);
            s += __shfl_xor(s, 4, 64);
            float pp = __expf(s * 0.125f);
            const __half2* vh = (const __half2*)&vraw[p];
            float2 v0 = __half22float2(vh[0]), v1 = __half22float2(vh[1]);
            float2 v2 = __half22float2(vh[2]), v3 = __half22float2(vh[3]);
            l_run += pp;
            o0.x += pp * (v0.x + e0.x); o0.y += pp * (v0.y + e0.y);
            o0.z += pp * (v1.x + e0.z); o0.w += pp * (v1.y + e0.w);
            o1.x += pp * (v2.x + e1.x); o1.y += pp * (v2.y + e1.y);
            o1.z += pp * (v3.x + e1.z); o1.w += pp * (v3.y + e1.w);
        }
    }
    ((float4*)(s_o + w * 512))[ln * 2]     = o0;
    ((float4*)(s_o + w * 512))[ln * 2 + 1] = o1;
    if ((ln & 7) == 0) s_l[w * 8 + (ln >> 3)] = l_run;
    __syncthreads();
    {
        float o = 0.0f;
#pragma unroll
        for (int g = 0; g < 8; g++) o += s_o[g * 512 + t];
        int h = t >> 6;
        float lsum = 0.0f;
#pragma unroll
        for (int g = 0; g < 8; g++) lsum += s_l[g * 8 + h];
        s_ao[t] = o / lsum;
    }
    __syncthreads();

    // ---------- Wo [512 x 128], K-split ----------
    wait_vm0();
    gemv128(s_ao, wbuf, s_part, w, ln);
    wait_lgkm0();
    wstage_stripe(W1L + w * 128, 1024, lslice, ln);   // W1 col-stripe
    __syncthreads();
    float x = 0.0f;
    if (own) {
        x = bo[l * DIMM + d];
#pragma unroll
        for (int g = 0; g < 8; g++) x += s_part[g * 128 + d];
    }

    // ---------- fused gate1 + LN2 (single reduce pass) ----------
    const float* Wg1_l = Wg1 + l * 3 * DIMM;
    {
        float tex = own ? (x * Wg1_l[d] + res * Wg1_l[DIMM + d] + (x - res) * Wg1_l[2 * DIMM + d]) : 0.0f;
        float vals[6] = {tex,
                         own ? x : 0.0f, own ? x * x : 0.0f,
                         own ? x * res : 0.0f,
                         own ? res : 0.0f, own ? res * res : 0.0f};
        block_reduce_n<6>(vals, s_red);
        float g1 = 1.0f / (1.0f + __expf(-vals[0]));
        float sn  = g1 * vals[1] + (1.0f - g1) * vals[4];
        float sn2 = g1 * g1 * vals[2] + 2.0f * g1 * (1.0f - g1) * vals[3]
                  + (1.0f - g1) * (1.0f - g1) * vals[5];
        float m   = sn * (1.0f / 128.0f);
        float var = sn2 * (1.0f / 128.0f) - m * m;
        float n1v = x * g1 + res * (1.0f - g1);
        res = n1v;   // reuse: res now holds n1
        if (own) s_xn[d] = (n1v - m) * rsqrtf(var + 1e-5f) * ln2_g[l * DIMM + d] + ln2_b[l * DIMM + d];
    }
    __syncthreads();
    float n1 = res;

    // ---------- W1 [128 x 512] col-split + gelu ----------
    wait_vm0();
    {
        float2 a2 = gemv512cs(s_xn, wbuf, ln);
        wait_lgkm0();
        wstage16(W2L + w * 16384, lslice, ln);   // W2 contiguous K-slice
        if (ln < 32) {
            int p = ln & 31, cg = w * 64 + 2 * p;
            float2 o;
            o.x = gelu_exact(a2.x + b1[l * 4 * DIMM + cg]);
            o.y = gelu_exact(a2.y + b1[l * 4 * DIMM + cg + 1]);
            ((float2*)s_h)[w * 32 + p] = o;
        }
    }
    __syncthreads();

    // ---------- W2 [512 x 128], K-split ----------
    wait_vm0();
    gemv128(s_h, wbuf, s_part, w, ln);
    wait_lgkm0();
    if (l < DEPTH - 1) wstage_stripe(WqL + w * 128, 1024, lslice, ln);   // Wq stripe
    __syncthreads();
    float y = 0.0f;
    if (own) {
        y = b2[l * DIMM + d];
#pragma unroll
        for (int g = 0; g < 8; g++) y += s_part[g * 128 + d];
    }

    const float* Wg2_l = Wg2 + l * 3 * DIMM;
    if (l < DEPTH - 1) {
        // ---------- fused gate2 + LN1' ----------
        float tex = own ? (y * Wg2_l[d] + n1 * Wg2_l[DIMM + d] + (y - n1) * Wg2_l[2 * DIMM + d]) : 0.0f;
        float vals[6] = {tex,
                         own ? y : 0.0f, own ? y * y : 0.0f,
                         own ? y * n1 : 0.0f,
                         own ? n1 : 0.0f, own ? n1 * n1 : 0.0f};
        block_reduce_n<6>(vals, s_red);
        float g2 = 1.0f / (1.0f + __expf(-vals[0]));
        float sn  = g2 * vals[1] + (1.0f - g2) * vals[4];
        float sn2 = g2 * g2 * vals[2] + 2.0f * g2 * (1.0f - g2) * vals[3]
                  + (1.0f - g2) * (1.0f - g2) * vals[5];
        float m   = sn * (1.0f / 128.0f);
        float var = sn2 * (1.0f / 128.0f) - m * m;
        float n2 = y * g2 + n1 * (1.0f - g2);
        if (own) {
            nodes[bn * DIMM + d] = n2;
            s_xn[d] = (n2 - m) * rsqrtf(var + 1e-5f) * ln1_g[(l + 1) * DIMM + d]
                    + ln1_b[(l + 1) * DIMM + d];
        }
        __syncthreads();

        int p = ln & 31;
        int cg = w * 64 + 2 * p;

        // Wq
        wait_vm0();
        float2 q2 = gemv512cs(s_xn, wbuf, ln);
        wait_lgkm0();
        wstage_stripe(WkvL + w * 128, 2048, lslice, ln);   // Wk
        if (ln < 32) {
            float2 o;
            o.x = q2.x + bq[(l + 1) * INNER + cg];
            o.y = q2.y + bq[(l + 1) * INNER + cg + 1];
            ((float2*)(qb + (size_t)bn * INNER))[w * 32 + p] = o;
        }

        // Wk
        wait_vm0();
        float2 k2 = gemv512cs(s_xn, wbuf, ln);
        wait_lgkm0();
        wstage_stripe(WkvL + 1024 + w * 128, 2048, lslice, ln);   // Wv
        if (ln < 32)
            ((__half2*)(hkout + (size_t)bn * INNER))[w * 32 + p] =
                __floats2half2_rn(k2.x + bkv[(l + 1) * 2 * INNER + cg],
                                  k2.y + bkv[(l + 1) * 2 * INNER + cg + 1]);

        // Wv
        wait_vm0();
        float2 v2 = gemv512cs(s_xn, wbuf, ln);
        if (ln < 32)
            ((__half2*)(hvout + (size_t)bn * INNER))[w * 32 + p] =
                __floats2half2_rn(v2.x + bkv[(l + 1) * 2 * INNER + INNER + cg],
                                  v2.y + bkv[(l + 1) * 2 * INNER + INNER + cg + 1]);
    } else {
        // ---------- fused gate2 + final contribution ----------
        float wl = own ? Wlin[d] : 0.0f;
        float tex = own ? (y * Wg2_l[d] + n1 * Wg2_l[DIMM + d] + (y - n1) * Wg2_l[2 * DIMM + d]) : 0.0f;
        float vals[3] = {tex, y * wl, n1 * wl};
        block_reduce_n<3>(vals, s_red);
        float g2 = 1.0f / (1.0f + __expf(-vals[0]));
        float tot = g2 * vals[1] + (1.0f - g2) * vals[2];
        if (t == 0) atomicAdd(out, tot);
    }
}

extern "C" void kernel_launch(void* const* d_in, const int* in_sizes, int n_in,
                              void* d_out, int out_size, void* d_ws, size_t ws_size,
                              hipStream_t stream) {
    const int*   indices = (const int*)d_in[0];
    const float* coords  = (const float*)d_in[1];
    const int*   bonds   = (const int*)d_in[2];
    const float* noise   = (const float*)d_in[3];
    const float* atom_emb= (const float*)d_in[4];
    const float* ln1_g   = (const float*)d_in[5];
    const float* ln1_b   = (const float*)d_in[6];
    const float* Wq      = (const float*)d_in[7];
    const float* bq      = (const float*)d_in[8];
    const float* Wkv     = (const float*)d_in[9];
    const float* bkv     = (const float*)d_in[10];
    const float* We      = (const float*)d_in[11];
    const float* be      = (const float*)d_in[12];
    const float* Wo      = (const float*)d_in[13];
    const float* bo      = (const float*)d_in[14];
    const float* Wg1     = (const float*)d_in[15];
    const float* ln2_g   = (const float*)d_in[16];
    const float* ln2_b   = (const float*)d_in[17];
    const float* W1      = (const float*)d_in[18];
    const float* b1      = (const float*)d_in[19];
    const float* W2      = (const float*)d_in[20];
    const float* b2      = (const float*)d_in[21];
    const float* Wg2     = (const float*)d_in[22];
    const float* Wlin    = (const float*)d_in[23];
    const float* blin    = (const float*)d_in[24];

    float*  ws    = (float*)d_ws;
    float*  nodes = ws;                         // 32768 f
    float*  qb    = nodes + NNODE * DIMM;       // 131072 f
    __half* hkb   = (__half*)(qb + NNODE * INNER);  // 2 slabs x 131072 halves
    __half* hvb   = hkb + 2 * NNODE * INNER;
    __half* hWq   = hvb + 2 * NNODE * INNER;
    __half* hWkv  = hWq + DEPTH * DIMM * INNER;
    __half* hWo   = hWkv + DEPTH * DIMM * 2 * INNER;
    __half* hW1   = hWo + DEPTH * INNER * DIMM;
    __half* hW2   = hW1 + DEPTH * DIMM * 4 * DIMM;

    k_cvt<<<1152, 512, 0, stream>>>(Wq, Wkv, Wo, W1, W2, hWq, hWkv, hWo, hW1, hW2,
                                    blin, (float*)d_out);
    k_pre<<<NNODE, 512, 0, stream>>>(indices, noise, atom_emb, ln1_g, ln1_b,
                                     hWq, bq, hWkv, bkv, nodes, qb, hkb, hvb);
    for (int l = 0; l < DEPTH; l++) {
        const __half* hkin = hkb + (size_t)(l & 1) * NNODE * INNER;
        const __half* hvin = hvb + (size_t)(l & 1) * NNODE * INNER;
        __half* hkout = hkb + (size_t)((l + 1) & 1) * NNODE * INNER;
        __half* hvout = hvb + (size_t)((l + 1) & 1) * NNODE * INNER;
        k_layer<<<NNODE, 512, 0, stream>>>(l, coords, bonds, We, be,
                                           qb, hkin, hvin, hkout, hvout,
                                           hWo, bo, Wg1, ln2_g, ln2_b, hW1, b1, hW2, b2,
                                           Wg2, ln1_g, ln1_b, hWq, bq, hWkv, bkv,
                                           nodes, Wlin, (float*)d_out);
    }
}

// Round 17
// 265.612 us; speedup vs baseline: 1.2884x; 1.2884x over previous
//
#include <hip/hip_runtime.h>
#include <hip/hip_fp16.h>
#include <math.h>

#define DEPTH 6
#define HEADS 8
#define BB    2
#define NN    128
#define EE    160
#define NF    127
#define DIMM  128
#define INNER 512
#define NNODE 256

__device__ __forceinline__ void gload16(const void* g, void* l) {
    __builtin_amdgcn_global_load_lds((const __attribute__((address_space(1))) void*)g,
                                     (__attribute__((address_space(3))) void*)l,
                                     16, 0, 0);
}

// wait this wave's outstanding vmem (vmcnt(0); lgkm/exp unconstrained)
__device__ __forceinline__ void wait_vm0() { __builtin_amdgcn_s_waitcnt(0x0f70); }
// drain this wave's LDS ops before slice overwrite
__device__ __forceinline__ void wait_lgkm0() { __builtin_amdgcn_s_waitcnt(0xC07F); }

// Per-wave 16 KB contiguous stage: 16 x (1 KB gload16). ldsslice wave-uniform.
__device__ __forceinline__ void wstage16(const char* gslice, char* ldsslice, int ln) {
#pragma unroll
    for (int i = 0; i < 16; i++)
        gload16(gslice + i * 1024 + ln * 16, ldsslice + i * 1024);
}
// Strided variant: 16 rows of 1 KB, global row stride `rowstride` bytes.
__device__ __forceinline__ void wstage16s(const char* gslice, int rowstride,
                                          char* ldsslice, int ln) {
#pragma unroll
    for (int i = 0; i < 16; i++)
        gload16(gslice + (size_t)i * rowstride + ln * 16, ldsslice + i * 1024);
}

__device__ __forceinline__ void fma8h(float4& a0, float4& a1, float s, float4 raw) {
    const __half2* hp = (const __half2*)&raw;
    float2 p0 = __half22float2(hp[0]), p1 = __half22float2(hp[1]);
    float2 p2 = __half22float2(hp[2]), p3 = __half22float2(hp[3]);
    a0.x += s * p0.x; a0.y += s * p0.y; a0.z += s * p1.x; a0.w += s * p1.y;
    a1.x += s * p2.x; a1.y += s * p2.y; a1.z += s * p3.x; a1.w += s * p3.y;
}

// GEMV unit, C=512 K=128, wave w owns rows [w*16, w*16+16). wbuf = 16 rows x 1KB.
__device__ __forceinline__ void gemv512(const float* act, const float* wbuf,
                                        float* s_part, int w, int ln) {
    float4 a0 = {0,0,0,0}, a1 = {0,0,0,0};
    const float4* w4 = (const float4*)wbuf;
#pragma unroll
    for (int r = 0; r < 16; r++)
        fma8h(a0, a1, act[w * 16 + r], w4[r * 64 + ln]);
    ((float4*)(s_part + w * 512))[ln * 2]     = a0;
    ((float4*)(s_part + w * 512))[ln * 2 + 1] = a1;
}

// GEMV unit, C=128 K=512, wave w owns rows [w*64, w*64+64). wbuf = 64 rows x 256B.
__device__ __forceinline__ void gemv128(const float* act, const float* wbuf,
                                        float* s_part, int w, int ln) {
    float2 acc = {0, 0};
#pragma unroll 8
    for (int r = 0; r < 64; r++) {
        float raw = wbuf[r * 64 + ln];
        float2 p = __half22float2(*(const __half2*)&raw);
        float a = act[w * 64 + r];
        acc.x += a * p.x; acc.y += a * p.y;
    }
    s_part[w * 128 + ln * 2]     = acc.x;
    s_part[w * 128 + ln * 2 + 1] = acc.y;
}

// N-value block reduce (8 waves); results broadcast into vals[].
template <int N>
__device__ __forceinline__ void block_reduce_n(float* vals, float* sbuf) {
#pragma unroll
    for (int off = 32; off > 0; off >>= 1)
#pragma unroll
        for (int q = 0; q < N; q++) vals[q] += __shfl_xor(vals[q], off, 64);
    int wave = threadIdx.x >> 6;
    if ((threadIdx.x & 63) == 0)
#pragma unroll
        for (int q = 0; q < N; q++) sbuf[wave * N + q] = vals[q];
    __syncthreads();
#pragma unroll
    for (int q = 0; q < N; q++) {
        float r = 0.0f;
#pragma unroll
        for (int g = 0; g < 8; g++) r += sbuf[g * N + q];
        vals[q] = r;
    }
    __syncthreads();
}

__device__ __forceinline__ float gelu_exact(float a) {
    return 0.5f * a * (1.0f + erff(a * 0.70710678f));
}

// ---------- kernels ----------

__global__ __launch_bounds__(512) void k_cvt(const float* Wq, const float* Wkv,
                                             const float* Wo, const float* W1,
                                             const float* W2,
                                             __half* hWq, __half* hWkv, __half* hWo,
                                             __half* hW1, __half* hW2,
                                             const float* blin, float* out) {
    if (blockIdx.x == 0 && threadIdx.x == 0) out[0] = 256.0f * blin[0];
    int g = blockIdx.x * 512 + threadIdx.x;
    const float4* src; __half* dst; int off;
    if (g < 98304)       { src = (const float4*)Wq;  dst = hWq;  off = g; }
    else if (g < 294912) { src = (const float4*)Wkv; dst = hWkv; off = g - 98304; }
    else if (g < 393216) { src = (const float4*)Wo;  dst = hWo;  off = g - 294912; }
    else if (g < 491520) { src = (const float4*)W1;  dst = hW1;  off = g - 393216; }
    else                 { src = (const float4*)W2;  dst = hW2;  off = g - 491520; }
    float4 v = src[off];
    __half2* d2 = (__half2*)(dst + (size_t)off * 4);
    d2[0] = __floats2half2_rn(v.x, v.y);
    d2[1] = __floats2half2_rn(v.z, v.w);
}

__global__ __launch_bounds__(512, 1) void k_pre(const int* indices, const float* noise,
                                                const float* atom_emb,
                                                const float* ln1_g, const float* ln1_b,
                                                const __half* hWq, const float* bq,
                                                const __half* hWkv, const float* bkv,
                                                float* nodes, float* qb,
                                                __half* hk, __half* hv) {
    int bn = blockIdx.x;
    int t  = threadIdx.x;
    int d  = t & 127;
    bool own = (t < 128);
    int w = t >> 6, ln = t & 63;
    __shared__ float arena[32768];
    __shared__ float s_xn[128];
    __shared__ float s_red[48];
    __shared__ float s_part[4096];
    char*  lslice = (char*)arena + w * 16384;
    float* wbuf   = arena + w * 4096;

    // stage Wq immediately; DMA overlaps gather + LN
    const char* WqL  = (const char*)hWq;
    const char* WkvL = (const char*)hWkv;
    wstage16(WqL + w * 16384, lslice, ln);

    float nd = 0.0f;
    if (own) {
        int idx = indices[bn];
        nd = (d < NF) ? atom_emb[idx * NF + d] : noise[0];
        nodes[bn * DIMM + d] = nd;
    }
    float vals[2] = {own ? nd : 0.0f, own ? nd * nd : 0.0f};
    block_reduce_n<2>(vals, s_red);
    float m   = vals[0] * (1.0f / 128.0f);
    float var = vals[1] * (1.0f / 128.0f) - m * m;
    if (own) s_xn[d] = (nd - m) * rsqrtf(var + 1e-5f) * ln1_g[d] + ln1_b[d];
    __syncthreads();

    // Wq
    wait_vm0();
    gemv512(s_xn, wbuf, s_part, w, ln);
    wait_lgkm0();
    wstage16s(WkvL + (size_t)(w * 16) * 2048, 2048, lslice, ln);   // Wk
    __syncthreads();
    {
        float q = bq[t];
#pragma unroll
        for (int g = 0; g < 8; g++) q += s_part[g * 512 + t];
        qb[(size_t)bn * INNER + t] = q;
    }
    __syncthreads();

    // Wk
    wait_vm0();
    gemv512(s_xn, wbuf, s_part, w, ln);
    wait_lgkm0();
    wstage16s(WkvL + (size_t)(w * 16) * 2048 + 1024, 2048, lslice, ln);   // Wv
    __syncthreads();
    {
        float k = bkv[t];
#pragma unroll
        for (int g = 0; g < 8; g++) k += s_part[g * 512 + t];
        hk[(size_t)bn * INNER + t] = __float2half(k);
    }
    __syncthreads();

    // Wv
    wait_vm0();
    gemv512(s_xn, wbuf, s_part, w, ln);
    __syncthreads();
    {
        float v = bkv[INNER + t];
#pragma unroll
        for (int g = 0; g < 8; g++) v += s_part[g * 512 + t];
        hv[(size_t)bn * INNER + t] = __float2half(v);
    }
}

__global__ __launch_bounds__(512, 1) void k_layer(int l,
        const float* coords, const int* bonds,
        const float* We, const float* be,
        float* qb, const __half* hkin, const __half* hvin,
        __half* hkout, __half* hvout,
        const __half* hWo, const float* bo, const float* Wg1,
        const float* ln2_g, const float* ln2_b,
        const __half* hW1, const float* b1,
        const __half* hW2, const float* b2,
        const float* Wg2,
        const float* ln1_g, const float* ln1_b,
        const __half* hWq, const float* bq,
        const __half* hWkv, const float* bkv,
        float* nodes, const float* Wlin, float* out) {
    int bn = blockIdx.x;
    int b = bn >> 7, i = bn & 127;
    int t = threadIdx.x;
    int d = t & 127;
    bool own = (t < 128);
    int w = t >> 6, ln = t & 63;

    __shared__ float arena[32768];     // per-wave weight slices (16 KB each)
    __shared__ float scoord[384];
    __shared__ float sedge[384];
    __shared__ int   sadj[128];
    __shared__ float s_l[64];
    __shared__ float s_ao[512];
    __shared__ float s_h[512];
    __shared__ float s_xn[128];
    __shared__ float s_red[48];
    __shared__ float s_part[4096];     // aliased as s_o (8 waves x 512) in attention
    float* s_o = s_part;
    char*  lslice = (char*)arena + w * 16384;
    float* wbuf   = arena + w * 4096;

    const char* WoL  = (const char*)(hWo + (size_t)l * INNER * DIMM);
    const char* W1L  = (const char*)(hW1 + (size_t)l * DIMM * 4 * DIMM);
    const char* W2L  = (const char*)(hW2 + (size_t)l * 4 * DIMM * DIMM);
    const char* WqL  = (const char*)(hWq + (size_t)(l + 1) * DIMM * INNER);
    const char* WkvL = (const char*)(hWkv + (size_t)(l + 1) * DIMM * 2 * INNER);

    // stage Wo immediately; DMA overlaps the whole attention phase
    wstage16(WoL + w * 16384, lslice, ln);

    // ---------- attention: wave w owns j in [w*16, w*16+16); 64 lanes = 512 dims ----------
    const float4* qR4 = (const float4*)(qb + (size_t)bn * INNER);
    const float4* WeR = (const float4*)(We + (size_t)l * 3 * INNER);
    float4 qa  = qR4[ln * 2],        qz  = qR4[ln * 2 + 1];
    float4 w0a = WeR[ln * 2],        w0z = WeR[ln * 2 + 1];
    float4 w1a = WeR[128 + ln * 2],  w1z = WeR[129 + ln * 2];
    float4 w2a = WeR[256 + ln * 2],  w2z = WeR[257 + ln * 2];
    float4 bea = ((const float4*)(be + (size_t)l * INNER))[ln * 2];
    float4 bez = ((const float4*)(be + (size_t)l * INNER))[ln * 2 + 1];
    float res = own ? nodes[bn * DIMM + d] : 0.0f;

    if (t < 3 * NN) scoord[t] = coords[b * 3 * NN + t];
    if (t < NN) sadj[t] = 0;
    __syncthreads();
    if (t < EE) {
        int e0 = bonds[2 * t], e1 = bonds[2 * t + 1];
        if (e0 == i) sadj[e1] = 1;
        if (e1 == i) sadj[e0] = 1;
    }
    __syncthreads();
    if (t < NN) {
        int j = t;
        float msk = sadj[j] ? 1.0f : 0.0f;
        sedge[3 * j + 0] = msk * (scoord[3 * i + 0] - scoord[3 * j + 0]);
        sedge[3 * j + 1] = msk * (scoord[3 * i + 1] - scoord[3 * j + 1]);
        sedge[3 * j + 2] = msk * (scoord[3 * i + 2] - scoord[3 * j + 2]);
    }
    __syncthreads();

    const float4* kR = (const float4*)(hkin + (size_t)b * NN * INNER);   // 8 halves/elt
    const float4* vR = (const float4*)(hvin + (size_t)b * NN * INNER);
    float l_run = 0.0f;
    float4 o0 = {0, 0, 0, 0}, o1 = {0, 0, 0, 0};
    int j0 = w * 16;
#pragma unroll
    for (int base = 0; base < 16; base += 4) {
        float4 kraw[4], vraw[4];
#pragma unroll
        for (int p = 0; p < 4; p++) {
            int j = j0 + base + p;
            kraw[p] = kR[j * 64 + ln];
            vraw[p] = vR[j * 64 + ln];
        }
#pragma unroll
        for (int p = 0; p < 4; p++) {
            int j = j0 + base + p;
            float ex = sedge[3 * j], ey = sedge[3 * j + 1], ez = sedge[3 * j + 2];
            float4 e0, e1;
            e0.x = bea.x + ex * w0a.x + ey * w1a.x + ez * w2a.x;
            e0.y = bea.y + ex * w0a.y + ey * w1a.y + ez * w2a.y;
            e0.z = bea.z + ex * w0a.z + ey * w1a.z + ez * w2a.z;
            e0.w = bea.w + ex * w0a.w + ey * w1a.w + ez * w2a.w;
            e1.x = bez.x + ex * w0z.x + ey * w1z.x + ez * w2z.x;
            e1.y = bez.y + ex * w0z.y + ey * w1z.y + ez * w2z.y;
            e1.z = bez.z + ex * w0z.z + ey * w1z.z + ez * w2z.z;
            e1.w = bez.w + ex * w0z.w + ey * w1z.w + ez * w2z.w;
            const __half2* kh = (const __half2*)&kraw[p];
            float2 k0 = __half22float2(kh[0]), k1 = __half22float2(kh[1]);
            float2 k2 = __half22float2(kh[2]), k3 = __half22float2(kh[3]);
            float s = qa.x * (k0.x + e0.x) + qa.y * (k0.y + e0.y)
                    + qa.z * (k1.x + e0.z) + qa.w * (k1.y + e0.w)
                    + qz.x * (k2.x + e1.x) + qz.y * (k2.y + e1.y)
                    + qz.z * (k3.x + e1.z) + qz.w * (k3.y + e1.w);
            s += __shfl_xor(s, 1, 64);
            s += __shfl_xor(s, 2, 64);
            s += __shfl_xor(s, 4, 64);
            float pp = __expf(s * 0.125f);
            const __half2* vh = (const __half2*)&vraw[p];
            float2 v0 = __half22float2(vh[0]), v1 = __half22float2(vh[1]);
            float2 v2 = __half22float2(vh[2]), v3 = __half22float2(vh[3]);
            l_run += pp;
            o0.x += pp * (v0.x + e0.x); o0.y += pp * (v0.y + e0.y);
            o0.z += pp * (v1.x + e0.z); o0.w += pp * (v1.y + e0.w);
            o1.x += pp * (v2.x + e1.x); o1.y += pp * (v2.y + e1.y);
            o1.z += pp * (v3.x + e1.z); o1.w += pp * (v3.y + e1.w);
        }
    }
    ((float4*)(s_o + w * 512))[ln * 2]     = o0;
    ((float4*)(s_o + w * 512))[ln * 2 + 1] = o1;
    if ((ln & 7) == 0) s_l[w * 8 + (ln >> 3)] = l_run;
    __syncthreads();
    {
        float o = 0.0f;
#pragma unroll
        for (int g = 0; g < 8; g++) o += s_o[g * 512 + t];
        int h = t >> 6;
        float lsum = 0.0f;
#pragma unroll
        for (int g = 0; g < 8; g++) lsum += s_l[g * 8 + h];
        s_ao[t] = o / lsum;
    }
    __syncthreads();

    // ---------- Wo [512 x 128], K-split ----------
    wait_vm0();
    gemv128(s_ao, wbuf, s_part, w, ln);
    wait_lgkm0();
    wstage16(W1L + w * 16384, lslice, ln);   // W1 DMA flies during gate1/LN2
    __syncthreads();
    float x = 0.0f;
    if (own) {
        x = bo[l * DIMM + d];
#pragma unroll
        for (int g = 0; g < 8; g++) x += s_part[g * 128 + d];
    }

    // ---------- fused gate1 + LN2 (single reduce pass) ----------
    const float* Wg1_l = Wg1 + l * 3 * DIMM;
    float n1;
    {
        float tex = own ? (x * Wg1_l[d] + res * Wg1_l[DIMM + d] + (x - res) * Wg1_l[2 * DIMM + d]) : 0.0f;
        float vals[6] = {tex,
                         own ? x : 0.0f, own ? x * x : 0.0f,
                         own ? x * res : 0.0f,
                         own ? res : 0.0f, own ? res * res : 0.0f};
        block_reduce_n<6>(vals, s_red);
        float g1 = 1.0f / (1.0f + __expf(-vals[0]));
        float sn  = g1 * vals[1] + (1.0f - g1) * vals[4];
        float sn2 = g1 * g1 * vals[2] + 2.0f * g1 * (1.0f - g1) * vals[3]
                  + (1.0f - g1) * (1.0f - g1) * vals[5];
        float m   = sn * (1.0f / 128.0f);
        float var = sn2 * (1.0f / 128.0f) - m * m;
        n1 = x * g1 + res * (1.0f - g1);
        if (own) s_xn[d] = (n1 - m) * rsqrtf(var + 1e-5f) * ln2_g[l * DIMM + d] + ln2_b[l * DIMM + d];
    }
    __syncthreads();

    // ---------- W1 [128 x 512] + gelu ----------
    wait_vm0();
    gemv512(s_xn, wbuf, s_part, w, ln);
    wait_lgkm0();
    wstage16(W2L + w * 16384, lslice, ln);   // W2 DMA flies during gelu combine
    __syncthreads();
    {
        float a = b1[l * 4 * DIMM + t];
#pragma unroll
        for (int g = 0; g < 8; g++) a += s_part[g * 512 + t];
        s_h[t] = gelu_exact(a);
    }
    __syncthreads();

    // ---------- W2 [512 x 128], K-split ----------
    wait_vm0();
    gemv128(s_h, wbuf, s_part, w, ln);
    wait_lgkm0();
    if (l < DEPTH - 1) wstage16(WqL + w * 16384, lslice, ln);   // Wq DMA
    __syncthreads();
    float y = 0.0f;
    if (own) {
        y = b2[l * DIMM + d];
#pragma unroll
        for (int g = 0; g < 8; g++) y += s_part[g * 128 + d];
    }

    const float* Wg2_l = Wg2 + l * 3 * DIMM;
    if (l < DEPTH - 1) {
        // ---------- fused gate2 + LN1' (single reduce pass) ----------
        float tex = own ? (y * Wg2_l[d] + n1 * Wg2_l[DIMM + d] + (y - n1) * Wg2_l[2 * DIMM + d]) : 0.0f;
        float vals[6] = {tex,
                         own ? y : 0.0f, own ? y * y : 0.0f,
                         own ? y * n1 : 0.0f,
                         own ? n1 : 0.0f, own ? n1 * n1 : 0.0f};
        block_reduce_n<6>(vals, s_red);
        float g2 = 1.0f / (1.0f + __expf(-vals[0]));
        float sn  = g2 * vals[1] + (1.0f - g2) * vals[4];
        float sn2 = g2 * g2 * vals[2] + 2.0f * g2 * (1.0f - g2) * vals[3]
                  + (1.0f - g2) * (1.0f - g2) * vals[5];
        float m   = sn * (1.0f / 128.0f);
        float var = sn2 * (1.0f / 128.0f) - m * m;
        float n2 = y * g2 + n1 * (1.0f - g2);
        if (own) {
            nodes[bn * DIMM + d] = n2;
            s_xn[d] = (n2 - m) * rsqrtf(var + 1e-5f) * ln1_g[(l + 1) * DIMM + d]
                    + ln1_b[(l + 1) * DIMM + d];
        }
        __syncthreads();

        // Wq
        wait_vm0();
        gemv512(s_xn, wbuf, s_part, w, ln);
        wait_lgkm0();
        wstage16s(WkvL + (size_t)(w * 16) * 2048, 2048, lslice, ln);   // Wk
        __syncthreads();
        {
            float q = bq[(l + 1) * INNER + t];
#pragma unroll
            for (int g = 0; g < 8; g++) q += s_part[g * 512 + t];
            qb[(size_t)bn * INNER + t] = q;
        }
        __syncthreads();

        // Wk
        wait_vm0();
        gemv512(s_xn, wbuf, s_part, w, ln);
        wait_lgkm0();
        wstage16s(WkvL + (size_t)(w * 16) * 2048 + 1024, 2048, lslice, ln);   // Wv
        __syncthreads();
        {
            float k = bkv[(l + 1) * 2 * INNER + t];
#pragma unroll
            for (int g = 0; g < 8; g++) k += s_part[g * 512 + t];
            hkout[(size_t)bn * INNER + t] = __float2half(k);
        }
        __syncthreads();

        // Wv
        wait_vm0();
        gemv512(s_xn, wbuf, s_part, w, ln);
        __syncthreads();
        {
            float v = bkv[(l + 1) * 2 * INNER + INNER + t];
#pragma unroll
            for (int g = 0; g < 8; g++) v += s_part[g * 512 + t];
            hvout[(size_t)bn * INNER + t] = __float2half(v);
        }
    } else {
        // ---------- fused gate2 + final contribution ----------
        float wl = own ? Wlin[d] : 0.0f;
        float tex = own ? (y * Wg2_l[d] + n1 * Wg2_l[DIMM + d] + (y - n1) * Wg2_l[2 * DIMM + d]) : 0.0f;
        float vals[3] = {tex, y * wl, n1 * wl};
        block_reduce_n<3>(vals, s_red);
        float g2 = 1.0f / (1.0f + __expf(-vals[0]));
        float tot = g2 * vals[1] + (1.0f - g2) * vals[2];
        if (t == 0) atomicAdd(out, tot);
    }
}

extern "C" void kernel_launch(void* const* d_in, const int* in_sizes, int n_in,
                              void* d_out, int out_size, void* d_ws, size_t ws_size,
                              hipStream_t stream) {
    const int*   indices = (const int*)d_in[0];
    const float* coords  = (const float*)d_in[1];
    const int*   bonds   = (const int*)d_in[2];
    const float* noise   = (const float*)d_in[3];
    const float* atom_emb= (const float*)d_in[4];
    const float* ln1_g   = (const float*)d_in[5];
    const float* ln1_b   = (const float*)d_in[6];
    const float* Wq      = (const float*)d_in[7];
    const float* bq      = (const float*)d_in[8];
    const float* Wkv     = (const float*)d_in[9];
    const float* bkv     = (const float*)d_in[10];
    const float* We      = (const float*)d_in[11];
    const float* be      = (const float*)d_in[12];
    const float* Wo      = (const float*)d_in[13];
    const float* bo      = (const float*)d_in[14];
    const float* Wg1     = (const float*)d_in[15];
    const float* ln2_g   = (const float*)d_in[16];
    const float* ln2_b   = (const float*)d_in[17];
    const float* W1      = (const float*)d_in[18];
    const float* b1      = (const float*)d_in[19];
    const float* W2      = (const float*)d_in[20];
    const float* b2      = (const float*)d_in[21];
    const float* Wg2     = (const float*)d_in[22];
    const float* Wlin    = (const float*)d_in[23];
    const float* blin    = (const float*)d_in[24];

    float*  ws    = (float*)d_ws;
    float*  nodes = ws;                         // 32768 f
    float*  qb    = nodes + NNODE * DIMM;       // 131072 f
    __half* hkb   = (__half*)(qb + NNODE * INNER);  // 2 slabs x 131072 halves
    __half* hvb   = hkb + 2 * NNODE * INNER;
    __half* hWq   = hvb + 2 * NNODE * INNER;
    __half* hWkv  = hWq + DEPTH * DIMM * INNER;
    __half* hWo   = hWkv + DEPTH * DIMM * 2 * INNER;
    __half* hW1   = hWo + DEPTH * INNER * DIMM;
    __half* hW2   = hW1 + DEPTH * DIMM * 4 * DIMM;

    k_cvt<<<1152, 512, 0, stream>>>(Wq, Wkv, Wo, W1, W2, hWq, hWkv, hWo, hW1, hW2,
                                    blin, (float*)d_out);
    k_pre<<<NNODE, 512, 0, stream>>>(indices, noise, atom_emb, ln1_g, ln1_b,
                                     hWq, bq, hWkv, bkv, nodes, qb, hkb, hvb);
    for (int l = 0; l < DEPTH; l++) {
        const __half* hkin = hkb + (size_t)(l & 1) * NNODE * INNER;
        const __half* hvin = hvb + (size_t)(l & 1) * NNODE * INNER;
        __half* hkout = hkb + (size_t)((l + 1) & 1) * NNODE * INNER;
        __half* hvout = hvb + (size_t)((l + 1) & 1) * NNODE * INNER;
        k_layer<<<NNODE, 512, 0, stream>>>(l, coords, bonds, We, be,
                                           qb, hkin, hvin, hkout, hvout,
                                           hWo, bo, Wg1, ln2_g, ln2_b, hW1, b1, hW2, b2,
                                           Wg2, ln1_g, ln1_b, hWq, bq, hWkv, bkv,
                                           nodes, Wlin, (float*)d_out);
    }
}